// Round 3
// baseline (442.862 us; speedup 1.0000x reference)
//
#include <hip/hip_runtime.h>
#include <hip/hip_bf16.h>
#include <stdint.h>

#define MD   128
#define LBAS 256

// ws layout: NkFull fp32 (256x128) @0, Mbf bf16 (128x128) @131072
#define MBF_OFF 131072ull
#define WS_NEED (131072ull + 32768ull)

typedef __attribute__((ext_vector_type(8))) __bf16 bf16x8;
typedef __attribute__((ext_vector_type(4))) float floatx4;
typedef __attribute__((ext_vector_type(8))) unsigned short ushortx8;
typedef __attribute__((ext_vector_type(4))) unsigned short ushortx4;

__device__ __forceinline__ float bf2f(unsigned short u){
  union { unsigned int i; float f; } v; v.i = ((unsigned int)u) << 16; return v.f;
}
__device__ __forceinline__ unsigned short f2bf(float x){
  union { float f; unsigned int i; } v; v.f = x;
  unsigned int r = v.i + 0x7FFFu + ((v.i >> 16) & 1u);
  return (unsigned short)(r >> 16);
}
__device__ __forceinline__ int detect_f32(const void* Bbasis){
  return ((const unsigned int*)Bbasis)[0] == 0x3F800000u;   // cos(pi)^4 == 1.0f
}

// ================= K0: Nk table + M->bf16 =================
__global__ __launch_bounds__(256) void nk2_kernel(const void* __restrict__ Acoeff,
                                                  const void* __restrict__ Bbasis,
                                                  const void* __restrict__ Mmat,
                                                  float* __restrict__ NkFull,
                                                  unsigned short* __restrict__ Mbf){
  int gid = blockIdx.x * 256 + threadIdx.x;
  const int isf = detect_f32(Bbasis);
  if (gid < LBAS * MD){
    int idx = gid >> 7, j = gid & 127;
    float a, b;
    if (isf){ a = ((const float*)Acoeff)[j*LBAS+idx]; b = ((const float*)Bbasis)[idx*MD+j]; }
    else    { a = bf2f(((const unsigned short*)Acoeff)[j*LBAS+idx]);
              b = bf2f(((const unsigned short*)Bbasis)[idx*MD+j]); }
    NkFull[gid] = a * b;
  } else {
    int m = gid - LBAS * MD;
    if (m < MD * MD){
      Mbf[m] = isf ? f2bf(((const float*)Mmat)[m]) : ((const unsigned short*)Mmat)[m];
    }
  }
}

// ================= K1: fused pool(2^4) + GEMM + epilogue =================
// Register-direct pooling: each owner thread (t<240: 15 windows x 16 col-chunks)
// loads its own 2(x2)x2(x3)x2(x4) window rows (8 x 32B f32 / 8 x 16B bf16),
// pools in registers. No S staging buffer, no LDS round trip -> 2 barriers/iter
// (was 4). Nk rows (16 x 128 f32) staged once per block. M in registers.
// LDS = 8448(Ct) + 8160(pp) + 4352(Ab) + 8192(sNk) = 29152 B.
__global__ __launch_bounds__(256, 4) void mega_kernel(const void* __restrict__ vec,
                                                      const float* __restrict__ NkFull,
                                                      const unsigned short* __restrict__ Mbf,
                                                      const void* __restrict__ Bbasis,
                                                      void* __restrict__ out){
  __shared__ __align__(16) float Ct[16 * 132];                 // MFMA output transpose
  __shared__ __align__(16) unsigned short pp[2][15][136];      // pooled-234 ping-pong (bf16)
  __shared__ __align__(16) unsigned short Ab[16 * 136];        // A-tile (row 15 unused)
  __shared__ __align__(16) float sNk[16 * 128];                // j1 x j4 Nk rows for this (w2,w3)

  // --- block decode: XCD-group same-b blocks (xcd = bid&7 -> {2b,2b+1}) ---
  const int xcd  = blockIdx.x & 7;
  const int slot = blockIdx.x >> 3;
  const int b    = xcd >> 1;
  const int s    = slot * 2 + (xcd & 1);
  if (s >= 225) return;
  const int w3 = s / 15;
  const int w2 = s - w3 * 15;
  const int t  = threadIdx.x;
  const int isf = detect_f32(Bbasis);

  const int wave = t >> 6, lane = t & 63;
  const int quad = lane >> 4, l16 = lane & 15;

  const int pw4   = t >> 4;            // window index along x4 (owner threads)
  const int pc8   = (t & 15) * 8;      // col base (8 floats)
  const int owner = (t < 240);

  // vec strides (elems): b 8388608, x1 524288, x2 32768, x3 2048, x4 128
  const size_t vbase0 = (size_t)b * 8388608 + (size_t)w2 * 32768 + (size_t)w3 * 2048;

  // 8 window rows: r = x2s*4 + x3s*2 + e4
  int offR[8];
#pragma unroll
  for (int r = 0; r < 8; ++r){
    const int x2s = r >> 2, x3s = (r >> 1) & 1, e4 = r & 1;
    offR[r] = x2s * 32768 + x3s * 2048 + (pw4 + e4) * 128 + pc8;
  }

  floatx4 pre[8][2];   // f32: 8 rows x 32B. bf16 path uses pre[r][0] as ushortx8.

  // --- prefetch x1 = 0 (HBM loads first) ---
  if (owner){
    if (isf){
      const float* vf = (const float*)vec + vbase0;
#pragma unroll
      for (int r = 0; r < 8; ++r){
        pre[r][0] = *(const floatx4*)(vf + offR[r]);
        pre[r][1] = *(const floatx4*)(vf + offR[r] + 4);
      }
    } else {
      const unsigned short* vh = (const unsigned short*)vec + vbase0;
#pragma unroll
      for (int r = 0; r < 8; ++r)
        *(ushortx8*)&pre[r][0] = *(const ushortx8*)(vh + offR[r]);
    }
  }

  // --- M fragments -> registers (loop-invariant; 16 VGPRs; L2-hot source) ---
  bf16x8 mfr[2][4];
#pragma unroll
  for (int cc = 0; cc < 2; ++cc)
#pragma unroll
    for (int s4 = 0; s4 < 4; ++s4)
      *(ushortx8*)&mfr[cc][s4] =
          *(const ushortx8*)(Mbf + ((wave * 2 + cc) * 16 + l16) * 128 + s4 * 32 + quad * 8);

  // --- stage the 16 Nk rows (j1 x j4) once; L2-hot source ---
  {
    const int j2f = (w2 & 3), j3f = (w3 & 3);
#pragma unroll
    for (int k = 0; k < 2; ++k){
      const int ci = k * 256 + t;            // 0..511 float4 chunks
      const int row16 = ci >> 5, c4 = (ci & 31) * 4;
      const int j1 = row16 >> 2, j4 = row16 & 3;
      const int nkrow = ((j1 * 4 + j2f) * 4 + j3f) * 4 + j4;
      *(floatx4*)&sNk[row16 * 128 + c4] = *(const floatx4*)&NkFull[nkrow * 128 + c4];
    }
  }

  for (int x1 = 0; x1 < 16; ++x1){
    // ---- pool x2,x3,x4 (2x2x2) fully in registers ----
    const int cb = x1 & 1, pbuf = cb ^ 1;
    float cur[8];
    if (owner){
      if (isf){
#pragma unroll
        for (int c = 0; c < 2; ++c){
          const floatx4 s0a = pre[0][c] + pre[4][c];   // x3a, x4a (x2 pair)
          const floatx4 s0b = pre[1][c] + pre[5][c];   // x3a, x4b
          const floatx4 s1a = pre[2][c] + pre[6][c];   // x3b, x4a
          const floatx4 s1b = pre[3][c] + pre[7][c];   // x3b, x4b
          const floatx4 cv4 = ((s0a + s0b) + (s1a + s1b)) * 0.125f;
#pragma unroll
          for (int e = 0; e < 4; ++e) cur[c * 4 + e] = cv4[e];
        }
      } else {
        const ushortx8 b0 = *(const ushortx8*)&pre[0][0];
        const ushortx8 b1 = *(const ushortx8*)&pre[1][0];
        const ushortx8 b2 = *(const ushortx8*)&pre[2][0];
        const ushortx8 b3 = *(const ushortx8*)&pre[3][0];
        const ushortx8 b4 = *(const ushortx8*)&pre[4][0];
        const ushortx8 b5 = *(const ushortx8*)&pre[5][0];
        const ushortx8 b6 = *(const ushortx8*)&pre[6][0];
        const ushortx8 b7 = *(const ushortx8*)&pre[7][0];
#pragma unroll
        for (int e = 0; e < 8; ++e){
          const float s0a = bf2f(b0[e]) + bf2f(b4[e]);
          const float s0b = bf2f(b1[e]) + bf2f(b5[e]);
          const float s1a = bf2f(b2[e]) + bf2f(b6[e]);
          const float s1b = bf2f(b3[e]) + bf2f(b7[e]);
          cur[e] = ((s0a + s0b) + (s1a + s1b)) * 0.125f;
        }
      }
    }

    // ---- prefetch x1+1 (regs free; overlaps MFMA + epilogue below) ----
    if (x1 < 15 && owner){
      if (isf){
        const float* vf = (const float*)vec + vbase0 + (size_t)(x1 + 1) * 524288;
#pragma unroll
        for (int r = 0; r < 8; ++r){
          pre[r][0] = *(const floatx4*)(vf + offR[r]);
          pre[r][1] = *(const floatx4*)(vf + offR[r] + 4);
        }
      } else {
        const unsigned short* vh = (const unsigned short*)vec + vbase0 + (size_t)(x1 + 1) * 524288;
#pragma unroll
        for (int r = 0; r < 8; ++r)
          *(ushortx8*)&pre[r][0] = *(const ushortx8*)(vh + offR[r]);
      }
    }

    // ---- pp write + A-tile build (pp is self-owned per thread: no barrier) ----
    if (owner){
      ushortx8 cv;
#pragma unroll
      for (int e = 0; e < 8; ++e) cv[e] = f2bf(cur[e]);
      *(ushortx8*)&pp[cb][pw4][pc8] = cv;
      if (x1 > 0){
        const ushortx8 pv = *(const ushortx8*)&pp[pbuf][pw4][pc8];
        ushortx8 av;
#pragma unroll
        for (int e = 0; e < 8; ++e) av[e] = f2bf((cur[e] + bf2f(pv[e])) * 0.5f);
        *(ushortx8*)&Ab[pw4 * 136 + pc8] = av;
      }
    }
    __syncthreads();   // Ab ready; prev-iter epilogue done (Ct free)

    if (x1 > 0){
      // ---- MFMA: wave w -> col tiles {2w, 2w+1}; B from registers ----
      floatx4 acc[2];
      acc[0] = (floatx4){0.f,0.f,0.f,0.f};
      acc[1] = (floatx4){0.f,0.f,0.f,0.f};
#pragma unroll
      for (int s4 = 0; s4 < 4; ++s4){
        const bf16x8 af = *(const bf16x8*)&Ab[l16 * 136 + s4 * 32 + quad * 8];
#pragma unroll
        for (int cc = 0; cc < 2; ++cc){
          acc[cc] = __builtin_amdgcn_mfma_f32_16x16x32_bf16(af, mfr[cc][s4], acc[cc], 0, 0, 0);
        }
      }
      // ---- transpose via Ct ----
#pragma unroll
      for (int cc = 0; cc < 2; ++cc)
#pragma unroll
        for (int reg = 0; reg < 4; ++reg)
          Ct[(quad * 4 + reg) * 132 + (wave * 2 + cc) * 16 + l16] = acc[cc][reg];
      __syncthreads();   // Ct ready

      // ---- epilogue: 15 rows x 512 B contiguous stores ----
      const int j1sel = (x1 - 1) & 3;
      const size_t outBase = ((size_t)(((b * 15 + (x1 - 1)) * 15 + w2) * 15 + w3)) * 15;
#pragma unroll
      for (int k = 0; k < 2; ++k){
        const int ci = k * 256 + t;
        if (ci < 480){
          const int row = ci >> 5, c4 = (ci & 31) * 4;
          const floatx4 v  = *(const floatx4*)&Ct[row * 132 + c4];
          const floatx4 nk = *(const floatx4*)&sNk[(j1sel * 4 + (row & 3)) * 128 + c4];
          floatx4 o;
#pragma unroll
          for (int e = 0; e < 4; ++e) o[e] = nk[e] - v[e];
          if (isf){
            *(floatx4*)((float*)out + (outBase + row) * 128 + c4) = o;
          } else {
            ushortx4 ob;
#pragma unroll
            for (int e = 0; e < 4; ++e) ob[e] = f2bf(o[e]);
            *(ushortx4*)((unsigned short*)out + (outBase + row) * 128 + c4) = ob;
          }
        }
      }
    }
  }
}

extern "C" void kernel_launch(void* const* d_in, const int* in_sizes, int n_in,
                              void* d_out, int out_size, void* d_ws, size_t ws_size,
                              hipStream_t stream) {
  const void* vec = d_in[0];   // (4,16,16,16,16,128)
  const void* Mm  = d_in[1];   // (128,128)
  const void* Ac  = d_in[2];   // (128,256)
  const void* Bb  = d_in[3];   // (256,128)

  float* NkFull = (float*)d_ws;
  unsigned short* Mbf = (unsigned short*)((char*)d_ws + MBF_OFF);

  nk2_kernel<<<192, 256, 0, stream>>>(Ac, Bb, Mm, NkFull, Mbf);
  mega_kernel<<<904, 256, 0, stream>>>(vec, NkFull, Mbf, Bb, d_out);
}

// Round 4
// 261.651 us; speedup vs baseline: 1.6926x; 1.6926x over previous
//
#include <hip/hip_runtime.h>
#include <hip/hip_bf16.h>
#include <stdint.h>

#define MD   128
#define LBAS 256

// ws layout: NkFull fp32 (256x128) @0, Mbf bf16 (128x128) @131072
#define MBF_OFF 131072ull
#define WS_NEED (131072ull + 32768ull)

typedef __attribute__((ext_vector_type(8))) __bf16 bf16x8;
typedef __attribute__((ext_vector_type(4))) float floatx4;
typedef __attribute__((ext_vector_type(8))) unsigned short ushortx8;
typedef __attribute__((ext_vector_type(4))) unsigned short ushortx4;

__device__ __forceinline__ float bf2f(unsigned short u){
  union { unsigned int i; float f; } v; v.i = ((unsigned int)u) << 16; return v.f;
}
__device__ __forceinline__ unsigned short f2bf(float x){
  union { float f; unsigned int i; } v; v.f = x;
  unsigned int r = v.i + 0x7FFFu + ((v.i >> 16) & 1u);
  return (unsigned short)(r >> 16);
}
__device__ __forceinline__ int detect_f32(const void* Bbasis){
  return ((const unsigned int*)Bbasis)[0] == 0x3F800000u;   // cos(pi)^4 == 1.0f
}

// ================= K0: Nk table + M->bf16 =================
__global__ __launch_bounds__(256) void nk2_kernel(const void* __restrict__ Acoeff,
                                                  const void* __restrict__ Bbasis,
                                                  const void* __restrict__ Mmat,
                                                  float* __restrict__ NkFull,
                                                  unsigned short* __restrict__ Mbf){
  int gid = blockIdx.x * 256 + threadIdx.x;
  const int isf = detect_f32(Bbasis);
  if (gid < LBAS * MD){
    int idx = gid >> 7, j = gid & 127;
    float a, b;
    if (isf){ a = ((const float*)Acoeff)[j*LBAS+idx]; b = ((const float*)Bbasis)[idx*MD+j]; }
    else    { a = bf2f(((const unsigned short*)Acoeff)[j*LBAS+idx]);
              b = bf2f(((const unsigned short*)Bbasis)[idx*MD+j]); }
    NkFull[gid] = a * b;
  } else {
    int m = gid - LBAS * MD;
    if (m < MD * MD){
      Mbf[m] = isf ? f2bf(((const float*)Mmat)[m]) : ((const unsigned short*)Mmat)[m];
    }
  }
}

// ================= K1: fused pool(2^4) + GEMM + epilogue =================
// S-staging base (proven no-spill, pre[4][2]=32 VGPR). Changes vs 87us version:
//  - pp ping-pong (per-thread-private) moved LDS->regs (prv[8]):  -8160 B LDS
//  - Ct transpose + 4th barrier removed: direct per-lane stores of nk-acc
//    in MFMA C/D layout (row=quad*4+reg, col=(wave*2+cc)*16+l16; row 15 skipped)
//  - full sNk (16x128 f32, 8KB) staged once per block (no per-iter Nk staging)
// LDS = 16896(S) + 4352(Ab) + 8192(sNk) = 29440 B; 3 barriers/iter.
__global__ __launch_bounds__(256, 4) void mega_kernel(const void* __restrict__ vec,
                                                      const float* __restrict__ NkFull,
                                                      const unsigned short* __restrict__ Mbf,
                                                      const void* __restrict__ Bbasis,
                                                      void* __restrict__ out){
  __shared__ __align__(16) float S[32 * 132];                  // staging (x2-pair sums)
  __shared__ __align__(16) unsigned short Ab[16 * 136];        // A-tile (row 15 unused)
  __shared__ __align__(16) float sNk[16 * 128];                // j1 x j4 Nk rows

  // --- block decode: XCD-group same-b blocks (xcd = bid&7 -> {2b,2b+1}) ---
  const int xcd  = blockIdx.x & 7;
  const int slot = blockIdx.x >> 3;
  const int b    = xcd >> 1;
  const int s    = slot * 2 + (xcd & 1);
  if (s >= 225) return;
  const int w3 = s / 15;
  const int w2 = s - w3 * 15;
  const int t  = threadIdx.x;
  const int isf = detect_f32(Bbasis);

  const int wave = t >> 6, lane = t & 63;
  const int quad = lane >> 4, l16 = lane & 15;

  // vec strides (elems): b 8388608, x1 524288, x2 32768, x3 2048, x4 128
  const size_t vbase0 = (size_t)b * 8388608 + (size_t)w2 * 32768 + (size_t)w3 * 2048;

  // --- per-thread static offsets ---
  int offF[4];   // fp32: 4 float4-chunks
#pragma unroll
  for (int k = 0; k < 4; ++k){
    const int ci = k * 256 + t;          // 0..1023
    const int row = ci >> 5;             // x3sub*16 + x4
    offF[k] = (row >> 4) * 2048 + (row & 15) * 128 + (ci & 31) * 4;
  }
  int offB[2];   // bf16: 2 ushortx8-chunks
#pragma unroll
  for (int k = 0; k < 2; ++k){
    const int ci = k * 256 + t;          // 0..511
    const int row = ci >> 4;
    offB[k] = (row >> 4) * 2048 + (row & 15) * 128 + (ci & 15) * 8;
  }

  floatx4 pre[4][2];   // prefetch regs (bf16 path bit-casts into pre[0..1])

  // --- prefetch x1 = 0 (issue HBM loads first) ---
  if (isf){
    const float* vf = (const float*)vec + vbase0;
#pragma unroll
    for (int k = 0; k < 4; ++k){
      pre[k][0] = *(const floatx4*)(vf + offF[k]);
      pre[k][1] = *(const floatx4*)(vf + offF[k] + 32768);
    }
  } else {
    const unsigned short* vh = (const unsigned short*)vec + vbase0;
#pragma unroll
    for (int k = 0; k < 2; ++k){
      *(ushortx8*)&pre[k][0] = *(const ushortx8*)(vh + offB[k]);
      *(ushortx8*)&pre[k][1] = *(const ushortx8*)(vh + offB[k] + 32768);
    }
  }

  // --- M fragments -> registers (loop-invariant; 16 VGPRs; L2-hot source) ---
  bf16x8 mfr[2][4];
#pragma unroll
  for (int cc = 0; cc < 2; ++cc)
#pragma unroll
    for (int s4 = 0; s4 < 4; ++s4)
      *(ushortx8*)&mfr[cc][s4] =
          *(const ushortx8*)(Mbf + ((wave * 2 + cc) * 16 + l16) * 128 + s4 * 32 + quad * 8);

  // --- stage the 16 Nk rows (j1 x j4) once; L2-hot source ---
  {
    const int j2f = (w2 & 3), j3f = (w3 & 3);
#pragma unroll
    for (int k = 0; k < 2; ++k){
      const int ci = k * 256 + t;            // 0..511 float4 chunks
      const int row16 = ci >> 5, c4 = (ci & 31) * 4;
      const int j1 = row16 >> 2, j4 = row16 & 3;
      const int nkrow = ((j1 * 4 + j2f) * 4 + j3f) * 4 + j4;
      *(floatx4*)&sNk[row16 * 128 + c4] = *(const floatx4*)&NkFull[nkrow * 128 + c4];
    }
  }

  const int pw4 = t >> 4;            // pooling coords (t<240 active)
  const int pc8 = (t & 15) * 8;
  const int owner = (t < 240);
  float prv[8];                      // per-thread pooled history (was pp LDS)

  for (int x1 = 0; x1 < 16; ++x1){
    __syncthreads();   // bar A: S free (pool reads done) / Ab reads done

    // ---- regs -> S (x2-pair sum) ----
    if (isf){
#pragma unroll
      for (int k = 0; k < 4; ++k){
        const int ci = k * 256 + t;
        const int row = ci >> 5, c4 = (ci & 31) * 4;
        floatx4 sv;
#pragma unroll
        for (int q = 0; q < 4; ++q) sv[q] = pre[k][0][q] + pre[k][1][q];
        *(floatx4*)&S[row * 132 + c4] = sv;
      }
    } else {
#pragma unroll
      for (int k = 0; k < 2; ++k){
        const int ci = k * 256 + t;
        const int row = ci >> 4, c8 = (ci & 15) * 8;
        const ushortx8 a = *(const ushortx8*)&pre[k][0];
        const ushortx8 c = *(const ushortx8*)&pre[k][1];
#pragma unroll
        for (int q = 0; q < 8; ++q) S[row * 132 + c8 + q] = bf2f(a[q]) + bf2f(c[q]);
      }
    }

    // ---- prefetch x1+1 (overlaps everything below) ----
    if (x1 < 15){
      if (isf){
        const float* vf = (const float*)vec + vbase0 + (size_t)(x1 + 1) * 524288;
#pragma unroll
        for (int k = 0; k < 4; ++k){
          pre[k][0] = *(const floatx4*)(vf + offF[k]);
          pre[k][1] = *(const floatx4*)(vf + offF[k] + 32768);
        }
      } else {
        const unsigned short* vh = (const unsigned short*)vec + vbase0 + (size_t)(x1 + 1) * 524288;
#pragma unroll
        for (int k = 0; k < 2; ++k){
          *(ushortx8*)&pre[k][0] = *(const ushortx8*)(vh + offB[k]);
          *(ushortx8*)&pre[k][1] = *(const ushortx8*)(vh + offB[k] + 32768);
        }
      }
    }
    __syncthreads();   // bar B: S ready

    // ---- pool x3,x4 (2x2) + A-tile build; history in regs ----
    if (owner){
      float cur[8];
      const int p0 = pw4 * 132 + pc8;
#pragma unroll
      for (int e = 0; e < 8; ++e)
        cur[e] = ((S[p0 + e] + S[p0 + 132 + e]) +
                  (S[p0 + 16 * 132 + e] + S[p0 + 17 * 132 + e])) * 0.125f;
      if (x1 > 0){
        ushortx8 av;
#pragma unroll
        for (int e = 0; e < 8; ++e) av[e] = f2bf((cur[e] + prv[e]) * 0.5f);
        *(ushortx8*)&Ab[pw4 * 136 + pc8] = av;
      }
#pragma unroll
      for (int e = 0; e < 8; ++e) prv[e] = cur[e];
    }
    __syncthreads();   // bar C: Ab ready

    if (x1 > 0){
      // ---- MFMA: wave w -> col tiles {2w, 2w+1}; B from registers ----
      floatx4 acc[2];
      acc[0] = (floatx4){0.f,0.f,0.f,0.f};
      acc[1] = (floatx4){0.f,0.f,0.f,0.f};
#pragma unroll
      for (int s4 = 0; s4 < 4; ++s4){
        const bf16x8 af = *(const bf16x8*)&Ab[l16 * 136 + s4 * 32 + quad * 8];
#pragma unroll
        for (int cc = 0; cc < 2; ++cc){
          acc[cc] = __builtin_amdgcn_mfma_f32_16x16x32_bf16(af, mfr[cc][s4], acc[cc], 0, 0, 0);
        }
      }

      // ---- direct epilogue: o = nk - acc, stored in C/D lane layout ----
      // row = quad*4+reg (skip 15), col = (wave*2+cc)*16 + l16
      const int j1sel = (x1 - 1) & 3;
      const size_t outBase = ((size_t)(((b * 15 + (x1 - 1)) * 15 + w2) * 15 + w3)) * 15;
      const int col0 = wave * 32 + l16;
#pragma unroll
      for (int cc = 0; cc < 2; ++cc){
        const int col = col0 + cc * 16;
#pragma unroll
        for (int reg = 0; reg < 4; ++reg){
          const int row = quad * 4 + reg;
          if (row < 15){
            const float nk = sNk[(j1sel * 4 + (row & 3)) * 128 + col];
            const float o = nk - acc[cc][reg];
            if (isf){
              ((float*)out)[(outBase + row) * 128 + col] = o;
            } else {
              ((unsigned short*)out)[(outBase + row) * 128 + col] = f2bf(o);
            }
          }
        }
      }
    }
  }
}

extern "C" void kernel_launch(void* const* d_in, const int* in_sizes, int n_in,
                              void* d_out, int out_size, void* d_ws, size_t ws_size,
                              hipStream_t stream) {
  const void* vec = d_in[0];   // (4,16,16,16,16,128)
  const void* Mm  = d_in[1];   // (128,128)
  const void* Ac  = d_in[2];   // (128,256)
  const void* Bb  = d_in[3];   // (256,128)

  float* NkFull = (float*)d_ws;
  unsigned short* Mbf = (unsigned short*)((char*)d_ws + MBF_OFF);

  nk2_kernel<<<192, 256, 0, stream>>>(Ac, Bb, Mm, NkFull, Mbf);
  mega_kernel<<<904, 256, 0, stream>>>(vec, NkFull, Mbf, Bb, d_out);
}